// Round 1
// baseline (567.447 us; speedup 1.0000x reference)
//
#include <hip/hip_runtime.h>
#include <math.h>

#define T_SEQ 2048
#define C_DIM 512
#define B_SZ  2
#define NHEAD 8
#define HD    64
#define DEXT  72   // 64 main dims + 8 freq dims

// ---------------------------------------------------------------------------
// Generic tiled f32 GEMM:  C[b] = alpha * (W[M,K] @ X[b][K,N] + bias) (+resid)
// grid: (N/64, ceil(M/64), B); block 256
// ---------------------------------------------------------------------------
__global__ __launch_bounds__(256)
void gemm_f32(const float* __restrict__ W, const float* __restrict__ X,
              const float* __restrict__ bias, const float* __restrict__ resid,
              float* __restrict__ Cout, int M, int N, int K, float alpha,
              long long outBatchStride)
{
    __shared__ __align__(16) float Wt[16][64];   // Wt[kk][m]
    __shared__ __align__(16) float Xt[16][64];   // Xt[kk][n]
    const int b = blockIdx.z;
    const float* Xb = X + (long long)b * K * N;
    float* Cb = Cout + (long long)b * outBatchStride;
    const float* Rb = resid ? resid + (long long)b * M * N : nullptr;
    const int m0 = blockIdx.y * 64, n0 = blockIdx.x * 64;
    const int tid = threadIdx.x;
    const int tx = tid & 15, ty = tid >> 4;
    const int wm  = m0 + (tid >> 2);
    const int wk4 = (tid & 3) * 4;
    const int xk  = tid >> 4;
    const int xn4 = (tid & 15) * 4;

    float acc[4][4] = {};
    for (int k0 = 0; k0 < K; k0 += 16) {
        float4 wv = make_float4(0.f, 0.f, 0.f, 0.f);
        if (wm < M)
            wv = *reinterpret_cast<const float4*>(&W[(long long)wm * K + k0 + wk4]);
        Wt[wk4 + 0][tid >> 2] = wv.x;
        Wt[wk4 + 1][tid >> 2] = wv.y;
        Wt[wk4 + 2][tid >> 2] = wv.z;
        Wt[wk4 + 3][tid >> 2] = wv.w;
        float4 xv = *reinterpret_cast<const float4*>(&Xb[(long long)(k0 + xk) * N + n0 + xn4]);
        *reinterpret_cast<float4*>(&Xt[xk][xn4]) = xv;
        __syncthreads();
#pragma unroll
        for (int kk = 0; kk < 16; ++kk) {
            float4 a = *reinterpret_cast<const float4*>(&Wt[kk][ty * 4]);
            float4 x4 = *reinterpret_cast<const float4*>(&Xt[kk][tx * 4]);
            float av[4] = {a.x, a.y, a.z, a.w};
            float bv[4] = {x4.x, x4.y, x4.z, x4.w};
#pragma unroll
            for (int i = 0; i < 4; ++i)
#pragma unroll
                for (int j = 0; j < 4; ++j) acc[i][j] += av[i] * bv[j];
        }
        __syncthreads();
    }
#pragma unroll
    for (int i = 0; i < 4; ++i) {
        int m = m0 + ty * 4 + i;
        if (m >= M) continue;
        float bs = bias ? bias[m] : 0.f;
#pragma unroll
        for (int j = 0; j < 4; ++j) {
            int n = n0 + tx * 4 + j;
            float v = alpha * (acc[i][j] + bs);
            if (Rb) v += Rb[(long long)m * N + n];
            Cb[(long long)m * N + n] = v;
        }
    }
}

// ---------------------------------------------------------------------------
// kext[2f][t]=cos(2*pi*t/(f+1)), kext[2f+1][t]=sin(...)  (shared by all b,h)
// ---------------------------------------------------------------------------
__global__ void kext_kernel(float* __restrict__ kext)
{
    int t = blockIdx.x * 256 + threadIdx.x;
    if (t >= T_SEQ) return;
#pragma unroll
    for (int f = 0; f < 4; ++f) {
        float a = 2.0f * (float)t / (float)(f + 1);
        kext[(long long)(2 * f) * T_SEQ + t]     = cospif(a);
        kext[(long long)(2 * f + 1) * T_SEQ + t] = sinpif(a);
    }
}

// ---------------------------------------------------------------------------
// From raw FQD[b][64][T] (rows 0..31 = Wqf@x+bqf, rows 32..63 = Wqd@x+bqd):
//   qext[bh][2f+c][s] = (FQ[h*4+f,s]/2) * {cos,sin}(2*pi*s/(f+1))
//   dcoef[bh][s]      = 0.25 * sum_f (f+1)*sigmoid(QD[h*4+f,s])
// grid: (T/256, B*NHEAD)
// ---------------------------------------------------------------------------
__global__ void coef_kernel(const float* __restrict__ fqd,
                            float* __restrict__ qext, float* __restrict__ dcoef)
{
    int s = blockIdx.x * 256 + threadIdx.x;
    int bh = blockIdx.y;
    int b = bh >> 3, h = bh & 7;
    const float* base = fqd + (long long)b * 64 * T_SEQ;
    float dsum = 0.f;
#pragma unroll
    for (int f = 0; f < 4; ++f) {
        float fq  = base[(long long)(h * 4 + f) * T_SEQ + s] * 0.5f;
        float zd  = base[(long long)(32 + h * 4 + f) * T_SEQ + s];
        float sig = 1.f / (1.f + __expf(-zd));
        dsum += (float)(f + 1) * sig;
        float a = 2.0f * (float)s / (float)(f + 1);
        qext[((long long)bh * 8 + 2 * f) * T_SEQ + s]     = fq * cospif(a);
        qext[((long long)bh * 8 + 2 * f + 1) * T_SEQ + s] = fq * sinpif(a);
    }
    dcoef[(long long)bh * T_SEQ + s] = 0.25f * dsum;
}

// ---------------------------------------------------------------------------
// Fused flash attention (non-causal, softmax over keys t).
//   S[t,s] = sum_{d<72} K~[d,t]*Q~[d,s]  - |t-s|*dcoef[s]   ; S[s,s] = -100
//   O[c,s] = sum_t softmax_t(S)[t,s] * V[c,t]
// Q~ rows 0..63 pre-scaled by 1/8; rows 64..71 = freq extension.
// grid: (T/64, B*NHEAD); block 256.  LDS ~55KB -> 2 wg/CU.
// ---------------------------------------------------------------------------
__global__ __launch_bounds__(256)
void attn_kernel(const float* __restrict__ Q, const float* __restrict__ K,
                 const float* __restrict__ V, const float* __restrict__ qext,
                 const float* __restrict__ dcoef, const float* __restrict__ kext,
                 float* __restrict__ R)
{
    __shared__ __align__(16) float Qs[DEXT][64];      // [d][ss]
    __shared__ __align__(16) float U[DEXT * 64];      // union: K as [d*64+tt], V as [tt*68+cc]
    __shared__ __align__(16) float Sx[64][68];        // [tt][ss] (pad 68)
    __shared__ __align__(16) float mArr[64];
    __shared__ __align__(16) float lArr[64];
    __shared__ __align__(16) float scArr[64];
    __shared__ __align__(16) float dcs[64];

    const int bh = blockIdx.y;
    const int b = bh >> 3, h = bh & 7;
    const int s0 = blockIdx.x * 64;
    const long long chanBase = ((long long)b * C_DIM + h * HD) * T_SEQ;
    const float* Qb = Q + chanBase;
    const float* Kb = K + chanBase;
    const float* Vb = V + chanBase;
    const float* qe = qext + (long long)bh * 8 * T_SEQ;
    const float* dcp = dcoef + (long long)bh * T_SEQ;
    const int tid = threadIdx.x;
    const int tx = tid & 15, ty = tid >> 4;

    for (int i = tid; i < DEXT * 64; i += 256) {
        int d = i >> 6, ss = i & 63;
        Qs[d][ss] = (d < HD) ? Qb[(long long)d * T_SEQ + s0 + ss]
                             : qe[(long long)(d - HD) * T_SEQ + s0 + ss];
    }
    if (tid < 64) {
        dcs[tid] = dcp[s0 + tid];
        mArr[tid] = -1e30f;
        lArr[tid] = 0.f;
    }
    float O[4][4] = {};
    __syncthreads();
    float4 dc4 = *reinterpret_cast<const float4*>(&dcs[tx * 4]);
    float dcv[4] = {dc4.x, dc4.y, dc4.z, dc4.w};

    for (int t0 = 0; t0 < T_SEQ; t0 += 64) {
        // phase A: load K tile (72 x 64) into U
        for (int i = tid; i < DEXT * 64; i += 256) {
            int d = i >> 6, tt = i & 63;
            U[d * 64 + tt] = (d < HD) ? Kb[(long long)d * T_SEQ + t0 + tt]
                                      : kext[(long long)(d - HD) * T_SEQ + t0 + tt];
        }
        __syncthreads();
        // phase B: S = K^T Q (+decay, mask), write to Sx
        float sacc[4][4] = {};
        for (int d = 0; d < DEXT; ++d) {
            float4 kv = *reinterpret_cast<const float4*>(&U[d * 64 + ty * 4]);
            float4 qv = *reinterpret_cast<const float4*>(&Qs[d][tx * 4]);
            float av[4] = {kv.x, kv.y, kv.z, kv.w};
            float bv[4] = {qv.x, qv.y, qv.z, qv.w};
#pragma unroll
            for (int i = 0; i < 4; ++i)
#pragma unroll
                for (int j = 0; j < 4; ++j) sacc[i][j] += av[i] * bv[j];
        }
#pragma unroll
        for (int i = 0; i < 4; ++i) {
            int t = t0 + ty * 4 + i;
#pragma unroll
            for (int j = 0; j < 4; ++j) {
                int s = s0 + tx * 4 + j;
                float v = sacc[i][j] - fabsf((float)(t - s)) * dcv[j];
                if (t == s) v = -100.f;
                sacc[i][j] = v;
            }
            *reinterpret_cast<float4*>(&Sx[ty * 4 + i][tx * 4]) =
                make_float4(sacc[i][0], sacc[i][1], sacc[i][2], sacc[i][3]);
        }
        __syncthreads();
        // phase C: load V tile into U (as [tt*68+cc]); lanes<64: column max
        for (int i = tid; i < 64 * 64; i += 256) {
            int cc = i >> 6, tt = i & 63;
            U[tt * 68 + cc] = Vb[(long long)cc * T_SEQ + t0 + tt];
        }
        if (tid < 64) {
            float m = mArr[tid], cm = m;
            for (int tt = 0; tt < 64; ++tt) cm = fmaxf(cm, Sx[tt][tid]);
            scArr[tid] = __expf(m - cm);
            mArr[tid] = cm;
        }
        __syncthreads();
        // phase D: P = exp(S - m) -> Sx ; rescale O
        float4 m4 = *reinterpret_cast<const float4*>(&mArr[tx * 4]);
        float mv[4] = {m4.x, m4.y, m4.z, m4.w};
        float4 sc4 = *reinterpret_cast<const float4*>(&scArr[tx * 4]);
        float scv[4] = {sc4.x, sc4.y, sc4.z, sc4.w};
#pragma unroll
        for (int i = 0; i < 4; ++i) {
#pragma unroll
            for (int j = 0; j < 4; ++j) sacc[i][j] = __expf(sacc[i][j] - mv[j]);
            *reinterpret_cast<float4*>(&Sx[ty * 4 + i][tx * 4]) =
                make_float4(sacc[i][0], sacc[i][1], sacc[i][2], sacc[i][3]);
        }
#pragma unroll
        for (int i = 0; i < 4; ++i)
#pragma unroll
            for (int j = 0; j < 4; ++j) O[i][j] *= scv[j];
        __syncthreads();
        // phase E: l update (lanes<64); PV accumulate (all)
        if (tid < 64) {
            float sum = 0.f;
            for (int tt = 0; tt < 64; ++tt) sum += Sx[tt][tid];
            lArr[tid] = lArr[tid] * scArr[tid] + sum;
        }
        for (int tt = 0; tt < 64; ++tt) {
            float4 vv = *reinterpret_cast<const float4*>(&U[tt * 68 + ty * 4]);
            float4 pv = *reinterpret_cast<const float4*>(&Sx[tt][tx * 4]);
            float av[4] = {vv.x, vv.y, vv.z, vv.w};
            float bv[4] = {pv.x, pv.y, pv.z, pv.w};
#pragma unroll
            for (int i = 0; i < 4; ++i)
#pragma unroll
                for (int j = 0; j < 4; ++j) O[i][j] += av[i] * bv[j];
        }
        __syncthreads();
    }
    float4 l4 = *reinterpret_cast<const float4*>(&lArr[tx * 4]);
    float inv[4] = {1.f / l4.x, 1.f / l4.y, 1.f / l4.z, 1.f / l4.w};
#pragma unroll
    for (int i = 0; i < 4; ++i) {
        float4 o4 = make_float4(O[i][0] * inv[0], O[i][1] * inv[1],
                                O[i][2] * inv[2], O[i][3] * inv[3]);
        *reinterpret_cast<float4*>(&R[chanBase + (long long)(ty * 4 + i) * T_SEQ + s0 + tx * 4]) = o4;
    }
}

// ---------------------------------------------------------------------------
extern "C" void kernel_launch(void* const* d_in, const int* in_sizes, int n_in,
                              void* d_out, int out_size, void* d_ws, size_t ws_size,
                              hipStream_t stream)
{
    const float* x   = (const float*)d_in[0];
    const float* Wq  = (const float*)d_in[1];
    const float* bq  = (const float*)d_in[2];
    const float* Wk  = (const float*)d_in[3];
    const float* bk  = (const float*)d_in[4];
    const float* Wc  = (const float*)d_in[5];
    const float* bc  = (const float*)d_in[6];
    const float* Wqf = (const float*)d_in[7];
    const float* bqf = (const float*)d_in[8];
    const float* Wqd = (const float*)d_in[9];
    const float* bqd = (const float*)d_in[10];
    const float* Wp  = (const float*)d_in[11];
    const float* bp  = (const float*)d_in[12];
    float* out = (float*)d_out;
    float* ws  = (float*)d_ws;

    const long long NBT = (long long)C_DIM * T_SEQ;          // 1,048,576
    float* q     = ws;                                       // 2*NBT
    float* k     = ws + 2 * NBT;                             // 2*NBT
    float* cn    = ws + 4 * NBT;                             // 2*NBT
    float* fqd   = ws + 6 * NBT;                             // B*64*T = 262144
    float* qext  = fqd + (long long)B_SZ * 64 * T_SEQ;       // B*8*8*T = 262144
    float* dcoef = qext + (long long)B_SZ * 64 * T_SEQ;      // B*8*T   = 32768
    float* kext  = dcoef + (long long)B_SZ * 8 * T_SEQ;      // 8*T     = 16384
    float* R     = kext + (long long)8 * T_SEQ;              // 2*NBT

    dim3 blk(256);
    dim3 g512(T_SEQ / 64, C_DIM / 64, B_SZ);
    dim3 g32(T_SEQ / 64, 1, B_SZ);

    // projections (Q scaled by 1/sqrt(HD)=1/8)
    hipLaunchKernelGGL(gemm_f32, g512, blk, 0, stream, Wq, x, bq, nullptr, q,
                       C_DIM, T_SEQ, C_DIM, 0.125f, 2LL * NBT / 2);
    hipLaunchKernelGGL(gemm_f32, g512, blk, 0, stream, Wk, x, bk, nullptr, k,
                       C_DIM, T_SEQ, C_DIM, 1.0f, 2LL * NBT / 2);
    hipLaunchKernelGGL(gemm_f32, g512, blk, 0, stream, Wc, x, bc, nullptr, cn,
                       C_DIM, T_SEQ, C_DIM, 1.0f, 2LL * NBT / 2);
    // freq / decay heads (raw): rows 0..31 FQ, rows 32..63 QD
    hipLaunchKernelGGL(gemm_f32, g32, blk, 0, stream, Wqf, x, bqf, nullptr, fqd,
                       32, T_SEQ, C_DIM, 1.0f, 64LL * T_SEQ);
    hipLaunchKernelGGL(gemm_f32, g32, blk, 0, stream, Wqd, x, bqd, nullptr,
                       fqd + 32LL * T_SEQ, 32, T_SEQ, C_DIM, 1.0f, 64LL * T_SEQ);

    hipLaunchKernelGGL(kext_kernel, dim3(T_SEQ / 256), blk, 0, stream, kext);
    hipLaunchKernelGGL(coef_kernel, dim3(T_SEQ / 256, B_SZ * NHEAD), blk, 0, stream,
                       fqd, qext, dcoef);

    hipLaunchKernelGGL(attn_kernel, dim3(T_SEQ / 64, B_SZ * NHEAD), blk, 0, stream,
                       q, k, cn, qext, dcoef, kext, R);

    // out = x + Wp @ R + bp
    hipLaunchKernelGGL(gemm_f32, g512, blk, 0, stream, Wp, R, bp, x, out,
                       C_DIM, T_SEQ, C_DIM, 1.0f, (long long)C_DIM * T_SEQ);
}

// Round 2
// 106.325 us; speedup vs baseline: 5.3369x; 5.3369x over previous
//
#include <hip/hip_runtime.h>
#include <math.h>

#define T_SEQ 2048
#define C_DIM 512
#define B_SZ  2
#define NHEAD 8
#define HD    64
#define DP    128           // padded Q/K head dims (bf16) -> 256B rows
#define MTOT  1600

typedef unsigned short u16t;
typedef unsigned int   u32t;
typedef float f32x4 __attribute__((ext_vector_type(4)));
typedef short s16x8 __attribute__((ext_vector_type(8)));

__device__ __forceinline__ u16t f2bf(float f) {
    union { float f; u32t u; } v; v.f = f;
    u32t r = v.u + 0x7fffu + ((v.u >> 16) & 1u);
    return (u16t)(r >> 16);
}
__device__ __forceinline__ u32t pack2(float a, float b) {
    return (u32t)f2bf(a) | ((u32t)f2bf(b) << 16);
}

#define GLD16(g, l) __builtin_amdgcn_global_load_lds( \
    (const __attribute__((address_space(1))) u32t*)(g), \
    (__attribute__((address_space(3))) u32t*)(l), 16, 0, 0)

// ---------------------------------------------------------------------------
// Weight/bias conversion: Wcat bf16 [1600][512], Wp bf16 [512][512], biascat
// ---------------------------------------------------------------------------
__global__ __launch_bounds__(256)
void wconv_kernel(const float* __restrict__ Wq, const float* __restrict__ Wk,
                  const float* __restrict__ Wc, const float* __restrict__ Wqf,
                  const float* __restrict__ Wqd, const float* __restrict__ Wp,
                  const float* __restrict__ bq, const float* __restrict__ bk,
                  const float* __restrict__ bc, const float* __restrict__ bqf,
                  const float* __restrict__ bqd,
                  u16t* __restrict__ Wcat, u16t* __restrict__ Wpbf,
                  float* __restrict__ biascat)
{
    int r = blockIdx.x, tid = threadIdx.x;
    if (r < MTOT) {
        const float* src;
        if (r < 512) src = Wq + (long long)r * C_DIM;
        else if (r < 1024) src = Wk + (long long)(r - 512) * C_DIM;
        else if (r < 1536) src = Wc + (long long)(r - 1024) * C_DIM;
        else if (r < 1568) src = Wqf + (long long)(r - 1536) * C_DIM;
        else src = Wqd + (long long)(r - 1568) * C_DIM;
        float2 v = *(const float2*)(src + tid * 2);
        *(u32t*)(Wcat + (long long)r * C_DIM + tid * 2) = pack2(v.x, v.y);
    } else if (r < MTOT + 512) {
        int rr = r - MTOT;
        float2 v = *(const float2*)(Wp + (long long)rr * C_DIM + tid * 2);
        *(u32t*)(Wpbf + (long long)rr * C_DIM + tid * 2) = pack2(v.x, v.y);
    } else {
        for (int i = tid; i < MTOT; i += 256) {
            float bv;
            if (i < 512) bv = bq[i];
            else if (i < 1024) bv = bk[i - 512];
            else if (i < 1536) bv = bc[i - 1024];
            else if (i < 1568) bv = bqf[i - 1536];
            else bv = bqd[i - 1568];
            biascat[i] = bv;
        }
    }
}

// ---------------------------------------------------------------------------
// x transpose: xT[b][t][c] bf16 from x[b][c][t] f32
// ---------------------------------------------------------------------------
__global__ __launch_bounds__(256)
void xt_kernel(const float* __restrict__ x, u16t* __restrict__ xT)
{
    __shared__ float tile[64][65];
    int b = blockIdx.z, c0 = blockIdx.y * 64, t0 = blockIdx.x * 64;
    int tid = threadIdx.x;
    const float* xb = x + ((long long)b * C_DIM + c0) * T_SEQ + t0;
#pragma unroll
    for (int rr = 0; rr < 16; ++rr) {
        int row = rr * 4 + (tid >> 6);
        tile[row][tid & 63] = xb[(long long)row * T_SEQ + (tid & 63)];
    }
    __syncthreads();
    int tt = tid >> 2, cs = (tid & 3) * 16;
    u32t ov[8];
#pragma unroll
    for (int u = 0; u < 8; ++u)
        ov[u] = pack2(tile[cs + u * 2][tt], tile[cs + u * 2 + 1][tt]);
    u16t* dst = xT + ((long long)b * T_SEQ + t0 + tt) * C_DIM + c0 + cs;
    *(uint4*)(dst) = make_uint4(ov[0], ov[1], ov[2], ov[3]);
    *(uint4*)(dst + 8) = make_uint4(ov[4], ov[5], ov[6], ov[7]);
}

// ---------------------------------------------------------------------------
// bf16 MFMA GEMM, 64x64 tile, BK=64, double-buffered global_load_lds staging.
//   mode 0: A=Wcat [1600][512], B=xT; epilogue scatters into Qbf/Kbf/Vbf/fqd
//   mode 1: A=Wpbf [512][512],  B=Rt; epilogue: out = acc + bp + x (f32)
// ---------------------------------------------------------------------------
__global__ __launch_bounds__(256)
void gemm_kernel(const u16t* __restrict__ A, const u16t* __restrict__ Bm,
                 const float* __restrict__ biasv, const float* __restrict__ x,
                 u16t* __restrict__ Qbf, u16t* __restrict__ Kbf,
                 u16t* __restrict__ Vbf, float* __restrict__ fqd,
                 float* __restrict__ outp, int mode)
{
    __shared__ u16t At[2][64 * 64];
    __shared__ u16t Bt[2][64 * 64];
    int b = blockIdx.z, m0 = blockIdx.y * 64, n0 = blockIdx.x * 64;
    int tid = threadIdx.x, w = tid >> 6, lane = tid & 63;
    int l16 = lane & 15, l4 = lane >> 4;
    const u16t* Bb = Bm + (long long)b * T_SEQ * C_DIM;

    auto stage = [&](int kt, int bufi) {
        int k0 = kt * 64;
        const u16t* srcb = (w < 2) ? A + (long long)m0 * C_DIM + k0
                                   : Bb + (long long)n0 * C_DIM + k0;
        u16t* dstb = (w < 2) ? &At[bufi][0] : &Bt[bufi][0];
#pragma unroll
        for (int i = 0; i < 4; ++i) {
            int rb = (w & 1) * 32 + i * 8;
            int row = rb + (lane >> 3);
            int c = (lane & 7) ^ (row & 7);
            GLD16(srcb + (long long)row * C_DIM + c * 8, dstb + rb * 64);
        }
    };

    f32x4 acc[4] = {};
    stage(0, 0);
    for (int kt = 0; kt < 8; ++kt) {
        __syncthreads();
        if (kt < 7) stage(kt + 1, (kt + 1) & 1);
        const u16t* Ab = At[kt & 1];
        const u16t* Bb2 = Bt[kt & 1];
        int nl = w * 16 + l16;
#pragma unroll
        for (int kb = 0; kb < 2; ++kb) {
            s16x8 bf = *(const s16x8*)(&Bb2[nl * 64 + (((kb * 4 + l4) ^ (l16 & 7)) * 8)]);
#pragma unroll
            for (int rt = 0; rt < 4; ++rt) {
                s16x8 af = *(const s16x8*)(&Ab[(rt * 16 + l16) * 64 + (((kb * 4 + l4) ^ (l16 & 7)) * 8)]);
                acc[rt] = __builtin_amdgcn_mfma_f32_16x16x32_bf16(af, bf, acc[rt], 0, 0, 0);
            }
        }
    }

    int n = n0 + w * 16 + l16;
    if (mode == 0) {
        if (m0 < 1024) {
            bool isQ = m0 < 512;
            int h = (isQ ? m0 : m0 - 512) >> 6;
            u16t* dst = (isQ ? Qbf : Kbf) + ((long long)(b * NHEAD + h) * T_SEQ + n) * DP;
            float sc = isQ ? 0.125f : 1.0f;
#pragma unroll
            for (int rt = 0; rt < 4; ++rt) {
                int d0 = rt * 16 + l4 * 4;
                int m = m0 + d0;
                float v0 = sc * (acc[rt][0] + biasv[m + 0]);
                float v1 = sc * (acc[rt][1] + biasv[m + 1]);
                float v2 = sc * (acc[rt][2] + biasv[m + 2]);
                float v3 = sc * (acc[rt][3] + biasv[m + 3]);
                *(uint2*)(dst + d0) = make_uint2(pack2(v0, v1), pack2(v2, v3));
            }
        } else if (m0 < 1536) {
#pragma unroll
            for (int rt = 0; rt < 4; ++rt)
#pragma unroll
                for (int j = 0; j < 4; ++j) {
                    int m = m0 + rt * 16 + l4 * 4 + j;
                    int c = m - 1024;
                    Vbf[((long long)b * C_DIM + c) * T_SEQ + n] = f2bf(acc[rt][j] + biasv[m]);
                }
        } else {
#pragma unroll
            for (int rt = 0; rt < 4; ++rt)
#pragma unroll
                for (int j = 0; j < 4; ++j) {
                    int m = m0 + rt * 16 + l4 * 4 + j;
                    fqd[((long long)b * 64 + (m - 1536)) * T_SEQ + n] = acc[rt][j] + biasv[m];
                }
        }
    } else {
#pragma unroll
        for (int rt = 0; rt < 4; ++rt)
#pragma unroll
            for (int j = 0; j < 4; ++j) {
                int m = m0 + rt * 16 + l4 * 4 + j;
                long long o = ((long long)b * C_DIM + m) * T_SEQ + n;
                outp[o] = acc[rt][j] + biasv[m] + x[o];
            }
    }
}

// ---------------------------------------------------------------------------
// Kbf freq extension: dims 64..71 = cos/sin(2*pi*t/p), 72..127 = 0
// ---------------------------------------------------------------------------
__global__ __launch_bounds__(256)
void kext_kernel(u16t* __restrict__ Kbf)
{
    int t = blockIdx.x * 256 + threadIdx.x;
    int bh = blockIdx.y;
    u32t e[4];
#pragma unroll
    for (int f = 0; f < 4; ++f) {
        float a = 2.0f * (float)t / (float)(f + 1);
        e[f] = pack2(cospif(a), sinpif(a));
    }
    u16t* row = Kbf + ((long long)bh * T_SEQ + t) * DP;
    *(uint4*)(row + 64) = make_uint4(e[0], e[1], e[2], e[3]);
    uint4 z = make_uint4(0, 0, 0, 0);
#pragma unroll
    for (int i = 0; i < 7; ++i) *(uint4*)(row + 72 + i * 8) = z;
}

// ---------------------------------------------------------------------------
// Qbf freq extension + decay coefficient from raw fqd
// ---------------------------------------------------------------------------
__global__ __launch_bounds__(256)
void coef_kernel(const float* __restrict__ fqd, u16t* __restrict__ Qbf,
                 float* __restrict__ dcoef)
{
    int s = blockIdx.x * 256 + threadIdx.x;
    int bh = blockIdx.y, b = bh >> 3, h = bh & 7;
    const float* base = fqd + (long long)b * 64 * T_SEQ;
    float dsum = 0.f;
    u32t e[4];
#pragma unroll
    for (int f = 0; f < 4; ++f) {
        float fq = base[(long long)(h * 4 + f) * T_SEQ + s] * 0.5f;
        float zd = base[(long long)(32 + h * 4 + f) * T_SEQ + s];
        dsum += (float)(f + 1) / (1.f + __expf(-zd));
        float a = 2.0f * (float)s / (float)(f + 1);
        e[f] = pack2(fq * cospif(a), fq * sinpif(a));
    }
    u16t* row = Qbf + ((long long)bh * T_SEQ + s) * DP;
    *(uint4*)(row + 64) = make_uint4(e[0], e[1], e[2], e[3]);
    uint4 z = make_uint4(0, 0, 0, 0);
#pragma unroll
    for (int i = 0; i < 7; ++i) *(uint4*)(row + 72 + i * 8) = z;
    dcoef[(long long)bh * T_SEQ + s] = 0.25f * dsum;
}

// ---------------------------------------------------------------------------
// MFMA flash attention. 4 waves; wave w owns s-columns [w*16, w*16+16).
// S[t,s] = sum_{d<96} K~[t,d] Q~[d,s] - |t-s|*dcoef[s]; diag=-100;
// online softmax over t; O = P^T-weighted V; writes Rt[b][s][c] bf16.
// ---------------------------------------------------------------------------
__global__ __launch_bounds__(256)
void attn_kernel(const u16t* __restrict__ Qbf, const u16t* __restrict__ Kbf,
                 const u16t* __restrict__ Vbf, const float* __restrict__ dcoef,
                 u16t* __restrict__ Rt)
{
    __shared__ u16t Qs[64 * DP];          // 16KB
    __shared__ u16t Kt[2][64 * DP];       // 32KB
    __shared__ u16t Vt[2][64 * 64];       // 16KB
    __shared__ u16t Pl[4][16 * 64];       // 8KB

    int bh = blockIdx.y, b = bh >> 3, h = bh & 7;
    int s0 = blockIdx.x * 64;
    int tid = threadIdx.x, w = tid >> 6, lane = tid & 63;
    int l16 = lane & 15, l4 = lane >> 4;
    const u16t* Qg = Qbf + (long long)bh * T_SEQ * DP;
    const u16t* Kg = Kbf + (long long)bh * T_SEQ * DP;
    const u16t* Vg = Vbf + ((long long)b * C_DIM + h * HD) * T_SEQ;

    // stage Q tile (once)
#pragma unroll
    for (int i = 0; i < 4; ++i) {
        int rb = w * 16 + i * 4;
        int row = rb + (lane >> 4);
        int c = (lane & 15) ^ (row & 7);
        GLD16(Qg + (long long)(s0 + row) * DP + c * 8, &Qs[rb * DP]);
    }

    auto stageKV = [&](int tt0, int bufi) {
#pragma unroll
        for (int i = 0; i < 4; ++i) {
            int rb = w * 16 + i * 4;
            int row = rb + (lane >> 4);
            int c = (lane & 15) ^ (row & 7);
            GLD16(Kg + (long long)(tt0 + row) * DP + c * 8, &Kt[bufi][rb * DP]);
        }
#pragma unroll
        for (int i = 0; i < 2; ++i) {
            int cb = w * 16 + i * 8;
            int cc = cb + (lane >> 3);
            int tc = (lane & 7) ^ (cc & 7);
            GLD16(Vg + (long long)cc * T_SEQ + tt0 + tc * 8, &Vt[bufi][cb * 64]);
        }
    };

    stageKV(0, 0);
    int sl = w * 16 + l16;
    float dc = dcoef[(long long)bh * T_SEQ + s0 + sl];
    float mrun = -1e30f, lrun = 0.f;
    f32x4 O4[4] = {};
    s16x8 qf[3];

    for (int it = 0; it < 32; ++it) {
        __syncthreads();   // compiler drains vmcnt(0) here: staged tile visible
        if (it + 1 < 32) stageKV((it + 1) * 64, (it + 1) & 1);
        if (it == 0) {
#pragma unroll
            for (int kb = 0; kb < 3; ++kb)
                qf[kb] = *(const s16x8*)(&Qs[sl * DP + (((kb * 4 + l4) ^ (l16 & 7)) * 8)]);
        }
        const u16t* Kb = Kt[it & 1];
        const u16t* Vb = Vt[it & 1];
        int t0 = it * 64;

        f32x4 sacc[4] = {};
#pragma unroll
        for (int kb = 0; kb < 3; ++kb)
#pragma unroll
            for (int rt = 0; rt < 4; ++rt) {
                s16x8 af = *(const s16x8*)(&Kb[(rt * 16 + l16) * DP + (((kb * 4 + l4) ^ (l16 & 7)) * 8)]);
                sacc[rt] = __builtin_amdgcn_mfma_f32_16x16x32_bf16(af, qf[kb], sacc[rt], 0, 0, 0);
            }

        int sg = s0 + sl;
        float cm = mrun;
        float pv[4][4];
#pragma unroll
        for (int rt = 0; rt < 4; ++rt) {
            int tb = t0 + rt * 16 + l4 * 4;
#pragma unroll
            for (int j = 0; j < 4; ++j) {
                int t = tb + j;
                float v = sacc[rt][j] - fabsf((float)(t - sg)) * dc;
                if (t == sg) v = -100.f;
                pv[rt][j] = v;
                cm = fmaxf(cm, v);
            }
        }
        cm = fmaxf(cm, __shfl_xor(cm, 16, 64));
        cm = fmaxf(cm, __shfl_xor(cm, 32, 64));
        float scale = __expf(mrun - cm);
        mrun = cm;
        float psum = 0.f;
#pragma unroll
        for (int rt = 0; rt < 4; ++rt)
#pragma unroll
            for (int j = 0; j < 4; ++j) {
                float p = __expf(pv[rt][j] - cm);
                pv[rt][j] = p;
                psum += p;
            }
        psum += __shfl_xor(psum, 16, 64);
        psum += __shfl_xor(psum, 32, 64);
        lrun = lrun * scale + psum;
#pragma unroll
        for (int rt = 0; rt < 4; ++rt) O4[rt] *= scale;

        // pack P^T[s][t] (bf16, swizzled) into wave-local strip
#pragma unroll
        for (int rt = 0; rt < 4; ++rt) {
            int tl = rt * 16 + l4 * 4;
            int cp = (tl >> 3) ^ (l16 & 7);
            *(uint2*)(&Pl[w][l16 * 64 + cp * 8 + (tl & 7)]) =
                make_uint2(pack2(pv[rt][0], pv[rt][1]), pack2(pv[rt][2], pv[rt][3]));
        }
        // PV
#pragma unroll
        for (int kb = 0; kb < 2; ++kb) {
            s16x8 pf = *(const s16x8*)(&Pl[w][l16 * 64 + (((kb * 4 + l4) ^ (l16 & 7)) * 8)]);
#pragma unroll
            for (int rt = 0; rt < 4; ++rt) {
                s16x8 vf = *(const s16x8*)(&Vb[(rt * 16 + l16) * 64 + (((kb * 4 + l4) ^ (l16 & 7)) * 8)]);
                O4[rt] = __builtin_amdgcn_mfma_f32_16x16x32_bf16(vf, pf, O4[rt], 0, 0, 0);
            }
        }
    }

    // epilogue: O/l -> bf16, LDS transpose bounce (reuse Kt[0]), coalesced store
    float inv = 1.f / lrun;
#pragma unroll
    for (int rt = 0; rt < 4; ++rt) {
        O4[rt] *= inv;
        int cb = rt * 16 + l4 * 4;
        int cp = (cb >> 3) ^ (sl & 7);
        *(uint2*)(&Kt[0][sl * 64 + cp * 8 + (cb & 7)]) =
            make_uint2(pack2(O4[rt][0], O4[rt][1]), pack2(O4[rt][2], O4[rt][3]));
    }
    __syncthreads();
    {
        int row = tid >> 2;
        int rsw = row & 7;
        u16t* dst = Rt + ((long long)b * T_SEQ + s0 + row) * C_DIM + h * HD;
#pragma unroll
        for (int i = 0; i < 2; ++i) {
            int cc = (tid & 3) + i * 4;
            uint4 v = *(const uint4*)(&Kt[0][row * 64 + ((cc ^ rsw) * 8)]);
            *(uint4*)(dst + cc * 8) = v;
        }
    }
}

// ---------------------------------------------------------------------------
extern "C" void kernel_launch(void* const* d_in, const int* in_sizes, int n_in,
                              void* d_out, int out_size, void* d_ws, size_t ws_size,
                              hipStream_t stream)
{
    const float* x   = (const float*)d_in[0];
    const float* Wq  = (const float*)d_in[1];
    const float* bq  = (const float*)d_in[2];
    const float* Wk  = (const float*)d_in[3];
    const float* bk  = (const float*)d_in[4];
    const float* Wc  = (const float*)d_in[5];
    const float* bc  = (const float*)d_in[6];
    const float* Wqf = (const float*)d_in[7];
    const float* bqf = (const float*)d_in[8];
    const float* Wqd = (const float*)d_in[9];
    const float* bqd = (const float*)d_in[10];
    const float* Wp  = (const float*)d_in[11];
    const float* bp  = (const float*)d_in[12];
    float* out = (float*)d_out;

    char* p = (char*)d_ws;
    u16t* Wcat = (u16t*)p;    p += (long long)MTOT * C_DIM * 2;
    u16t* Wpbf = (u16t*)p;    p += (long long)C_DIM * C_DIM * 2;
    float* biascat = (float*)p; p += MTOT * 4;
    u16t* xT = (u16t*)p;      p += (long long)B_SZ * T_SEQ * C_DIM * 2;
    u16t* Qbf = (u16t*)p;     p += (long long)16 * T_SEQ * DP * 2;
    u16t* Kbf = (u16t*)p;     p += (long long)16 * T_SEQ * DP * 2;
    u16t* Vbf = (u16t*)p;     p += (long long)B_SZ * C_DIM * T_SEQ * 2;
    float* fqd = (float*)p;   p += (long long)B_SZ * 64 * T_SEQ * 4;
    float* dcoef = (float*)p; p += (long long)16 * T_SEQ * 4;
    u16t* Rt = (u16t*)p;      p += (long long)B_SZ * T_SEQ * C_DIM * 2;

    dim3 blk(256);
    hipLaunchKernelGGL(wconv_kernel, dim3(MTOT + 512 + 1), blk, 0, stream,
                       Wq, Wk, Wc, Wqf, Wqd, Wp, bq, bk, bc, bqf, bqd,
                       Wcat, Wpbf, biascat);
    hipLaunchKernelGGL(xt_kernel, dim3(T_SEQ / 64, C_DIM / 64, B_SZ), blk, 0, stream,
                       x, xT);
    hipLaunchKernelGGL(gemm_kernel, dim3(T_SEQ / 64, MTOT / 64, B_SZ), blk, 0, stream,
                       Wcat, xT, biascat, nullptr, Qbf, Kbf, Vbf, fqd, nullptr, 0);
    hipLaunchKernelGGL(kext_kernel, dim3(T_SEQ / 256, 16), blk, 0, stream, Kbf);
    hipLaunchKernelGGL(coef_kernel, dim3(T_SEQ / 256, 16), blk, 0, stream,
                       fqd, Qbf, dcoef);
    hipLaunchKernelGGL(attn_kernel, dim3(T_SEQ / 64, 16), blk, 0, stream,
                       Qbf, Kbf, Vbf, dcoef, Rt);
    hipLaunchKernelGGL(gemm_kernel, dim3(T_SEQ / 64, C_DIM / 64, B_SZ), blk, 0, stream,
                       Wpbf, Rt, bp, (const float*)x, nullptr, nullptr, nullptr, nullptr,
                       out, 1);
}

// Round 3
// 63.779 us; speedup vs baseline: 8.8971x; 1.6671x over previous
//
#include <hip/hip_runtime.h>
#include <math.h>

#define T_SEQ 2048
#define C_DIM 512
#define B_SZ  2
#define NHEAD 8
#define HD    64
#define DP    128           // padded Q/K head dims (bf16) -> 256B rows
#define MTOT  1600
#define NTILE 32            // T_SEQ/64

typedef unsigned short u16t;
typedef unsigned int   u32t;
typedef float f32x4 __attribute__((ext_vector_type(4)));
typedef short s16x8 __attribute__((ext_vector_type(8)));

__device__ __forceinline__ u32t pack2(float a, float b) {
    u32t r;
    asm("v_cvt_pk_bf16_f32 %0, %1, %2" : "=v"(r) : "v"(a), "v"(b));
    return r;
}
__device__ __forceinline__ u16t f2bf(float f) {
    union { float f; u32t u; } v; v.f = f;
    u32t r = v.u + 0x7fffu + ((v.u >> 16) & 1u);
    return (u16t)(r >> 16);
}
__device__ __forceinline__ float bf2f(u16t h) {
    union { u32t u; float f; } v; v.u = (u32t)h << 16; return v.f;
}

#define GLD16(g, l) __builtin_amdgcn_global_load_lds( \
    (const __attribute__((address_space(1))) u32t*)(g), \
    (__attribute__((address_space(3))) u32t*)(l), 16, 0, 0)

// ---------------------------------------------------------------------------
// Weight/bias conversion: Wcat bf16 [1600][512], Wp bf16 [512][512], biascat
// ---------------------------------------------------------------------------
__global__ __launch_bounds__(256)
void wconv_kernel(const float* __restrict__ Wq, const float* __restrict__ Wk,
                  const float* __restrict__ Wc, const float* __restrict__ Wqf,
                  const float* __restrict__ Wqd, const float* __restrict__ Wp,
                  const float* __restrict__ bq, const float* __restrict__ bk,
                  const float* __restrict__ bc, const float* __restrict__ bqf,
                  const float* __restrict__ bqd,
                  u16t* __restrict__ Wcat, u16t* __restrict__ Wpbf,
                  float* __restrict__ biascat)
{
    int r = blockIdx.x, tid = threadIdx.x;
    if (r < MTOT) {
        const float* src;
        if (r < 512) src = Wq + (long long)r * C_DIM;
        else if (r < 1024) src = Wk + (long long)(r - 512) * C_DIM;
        else if (r < 1536) src = Wc + (long long)(r - 1024) * C_DIM;
        else if (r < 1568) src = Wqf + (long long)(r - 1536) * C_DIM;
        else src = Wqd + (long long)(r - 1568) * C_DIM;
        float2 v = *(const float2*)(src + tid * 2);
        *(u32t*)(Wcat + (long long)r * C_DIM + tid * 2) = pack2(v.x, v.y);
    } else if (r < MTOT + 512) {
        int rr = r - MTOT;
        float2 v = *(const float2*)(Wp + (long long)rr * C_DIM + tid * 2);
        *(u32t*)(Wpbf + (long long)rr * C_DIM + tid * 2) = pack2(v.x, v.y);
    } else {
        for (int i = tid; i < MTOT; i += 256) {
            float bv;
            if (i < 512) bv = bq[i];
            else if (i < 1024) bv = bk[i - 512];
            else if (i < 1536) bv = bc[i - 1024];
            else if (i < 1568) bv = bqf[i - 1536];
            else bv = bqd[i - 1568];
            biascat[i] = bv;
        }
    }
}

// ---------------------------------------------------------------------------
// x transpose: xT[b][t][c] bf16 from x[b][c][t] f32
// ---------------------------------------------------------------------------
__global__ __launch_bounds__(256)
void xt_kernel(const float* __restrict__ x, u16t* __restrict__ xT)
{
    __shared__ float tile[64][65];
    int b = blockIdx.z, c0 = blockIdx.y * 64, t0 = blockIdx.x * 64;
    int tid = threadIdx.x;
    const float* xb = x + ((long long)b * C_DIM + c0) * T_SEQ + t0;
#pragma unroll
    for (int rr = 0; rr < 16; ++rr) {
        int row = rr * 4 + (tid >> 6);
        tile[row][tid & 63] = xb[(long long)row * T_SEQ + (tid & 63)];
    }
    __syncthreads();
    int tt = tid >> 2, cs = (tid & 3) * 16;
    u32t ov[8];
#pragma unroll
    for (int u = 0; u < 8; ++u)
        ov[u] = pack2(tile[cs + u * 2][tt], tile[cs + u * 2 + 1][tt]);
    u16t* dst = xT + ((long long)b * T_SEQ + t0 + tt) * C_DIM + c0 + cs;
    *(uint4*)(dst) = make_uint4(ov[0], ov[1], ov[2], ov[3]);
    *(uint4*)(dst + 8) = make_uint4(ov[4], ov[5], ov[6], ov[7]);
}

// ---------------------------------------------------------------------------
// bf16 MFMA GEMM, 64x64 tile, BK=64, double-buffered global_load_lds staging.
//   mode 0: A=Wcat [1600][512], B=xT; epilogue scatters into Qbf/Kbf/Vbf/fqd
//   mode 1: A=Wpbf [512][512],  B=Rt; epilogue: out = acc + bp + x (f32)
// ---------------------------------------------------------------------------
__global__ __launch_bounds__(256)
void gemm_kernel(const u16t* __restrict__ A, const u16t* __restrict__ Bm,
                 const float* __restrict__ biasv, const float* __restrict__ x,
                 u16t* __restrict__ Qbf, u16t* __restrict__ Kbf,
                 u16t* __restrict__ Vbf, float* __restrict__ fqd,
                 float* __restrict__ outp, int mode)
{
    __shared__ u16t At[2][64 * 64];
    __shared__ u16t Bt[2][64 * 64];
    int b = blockIdx.z, m0 = blockIdx.y * 64, n0 = blockIdx.x * 64;
    int tid = threadIdx.x, w = tid >> 6, lane = tid & 63;
    int l16 = lane & 15, l4 = lane >> 4;
    const u16t* Bb = Bm + (long long)b * T_SEQ * C_DIM;

    auto stage = [&](int kt, int bufi) {
        int k0 = kt * 64;
        const u16t* srcb = (w < 2) ? A + (long long)m0 * C_DIM + k0
                                   : Bb + (long long)n0 * C_DIM + k0;
        u16t* dstb = (w < 2) ? &At[bufi][0] : &Bt[bufi][0];
#pragma unroll
        for (int i = 0; i < 4; ++i) {
            int rb = (w & 1) * 32 + i * 8;
            int row = rb + (lane >> 3);
            int c = (lane & 7) ^ (row & 7);
            GLD16(srcb + (long long)row * C_DIM + c * 8, dstb + rb * 64);
        }
    };

    f32x4 acc[4] = {};
    stage(0, 0);
    for (int kt = 0; kt < 8; ++kt) {
        __syncthreads();
        if (kt < 7) stage(kt + 1, (kt + 1) & 1);
        const u16t* Ab = At[kt & 1];
        const u16t* Bb2 = Bt[kt & 1];
        int nl = w * 16 + l16;
#pragma unroll
        for (int kb = 0; kb < 2; ++kb) {
            s16x8 bf = *(const s16x8*)(&Bb2[nl * 64 + (((kb * 4 + l4) ^ (l16 & 7)) * 8)]);
#pragma unroll
            for (int rt = 0; rt < 4; ++rt) {
                s16x8 af = *(const s16x8*)(&At[kt & 1][(rt * 16 + l16) * 64 + (((kb * 4 + l4) ^ (l16 & 7)) * 8)]);
                acc[rt] = __builtin_amdgcn_mfma_f32_16x16x32_bf16(af, bf, acc[rt], 0, 0, 0);
            }
            (void)Ab;
        }
    }

    int n = n0 + w * 16 + l16;
    if (mode == 0) {
        if (m0 < 1024) {
            bool isQ = m0 < 512;
            int h = (isQ ? m0 : m0 - 512) >> 6;
            u16t* dst = (isQ ? Qbf : Kbf) + ((long long)(b * NHEAD + h) * T_SEQ + n) * DP;
            float sc = isQ ? 0.125f : 1.0f;
#pragma unroll
            for (int rt = 0; rt < 4; ++rt) {
                int d0 = (rt * 16 + l4 * 4) & 63;
                int m = m0 + rt * 16 + l4 * 4;
                float v0 = sc * (acc[rt][0] + biasv[m + 0]);
                float v1 = sc * (acc[rt][1] + biasv[m + 1]);
                float v2 = sc * (acc[rt][2] + biasv[m + 2]);
                float v3 = sc * (acc[rt][3] + biasv[m + 3]);
                *(uint2*)(dst + d0) = make_uint2(pack2(v0, v1), pack2(v2, v3));
            }
        } else if (m0 < 1536) {
#pragma unroll
            for (int rt = 0; rt < 4; ++rt)
#pragma unroll
                for (int j = 0; j < 4; ++j) {
                    int m = m0 + rt * 16 + l4 * 4 + j;
                    int c = m - 1024;
                    Vbf[((long long)b * C_DIM + c) * T_SEQ + n] = f2bf(acc[rt][j] + biasv[m]);
                }
        } else {
#pragma unroll
            for (int rt = 0; rt < 4; ++rt)
#pragma unroll
                for (int j = 0; j < 4; ++j) {
                    int m = m0 + rt * 16 + l4 * 4 + j;
                    fqd[((long long)b * 64 + (m - 1536)) * T_SEQ + n] = acc[rt][j] + biasv[m];
                }
        }
    } else {
#pragma unroll
        for (int rt = 0; rt < 4; ++rt)
#pragma unroll
            for (int j = 0; j < 4; ++j) {
                int m = m0 + rt * 16 + l4 * 4 + j;
                long long o = ((long long)b * C_DIM + m) * T_SEQ + n;
                outp[o] = acc[rt][j] + biasv[m] + x[o];
            }
    }
}

// ---------------------------------------------------------------------------
// Kbf freq extension: dims 64..71 = cos/sin(2*pi*t/p), 72..127 = 0
// ---------------------------------------------------------------------------
__global__ __launch_bounds__(256)
void kext_kernel(u16t* __restrict__ Kbf)
{
    int t = blockIdx.x * 256 + threadIdx.x;
    int bh = blockIdx.y;
    u32t e[4];
#pragma unroll
    for (int f = 0; f < 4; ++f) {
        float a = 2.0f * (float)t / (float)(f + 1);
        e[f] = pack2(cospif(a), sinpif(a));
    }
    u16t* row = Kbf + ((long long)bh * T_SEQ + t) * DP;
    *(uint4*)(row + 64) = make_uint4(e[0], e[1], e[2], e[3]);
    uint4 z = make_uint4(0, 0, 0, 0);
#pragma unroll
    for (int i = 0; i < 7; ++i) *(uint4*)(row + 72 + i * 8) = z;
}

// ---------------------------------------------------------------------------
// Qbf freq extension + decay coefficient from raw fqd
// ---------------------------------------------------------------------------
__global__ __launch_bounds__(256)
void coef_kernel(const float* __restrict__ fqd, u16t* __restrict__ Qbf,
                 float* __restrict__ dcoef)
{
    int s = blockIdx.x * 256 + threadIdx.x;
    int bh = blockIdx.y, b = bh >> 3, h = bh & 7;
    const float* base = fqd + (long long)b * 64 * T_SEQ;
    float dsum = 0.f;
    u32t e[4];
#pragma unroll
    for (int f = 0; f < 4; ++f) {
        float fq = base[(long long)(h * 4 + f) * T_SEQ + s] * 0.5f;
        float zd = base[(long long)(32 + h * 4 + f) * T_SEQ + s];
        dsum += (float)(f + 1) / (1.f + __expf(-zd));
        float a = 2.0f * (float)s / (float)(f + 1);
        e[f] = pack2(fq * cospif(a), fq * sinpif(a));
    }
    u16t* row = Qbf + ((long long)bh * T_SEQ + s) * DP;
    *(uint4*)(row + 64) = make_uint4(e[0], e[1], e[2], e[3]);
    uint4 z = make_uint4(0, 0, 0, 0);
#pragma unroll
    for (int i = 0; i < 7; ++i) *(uint4*)(row + 72 + i * 8) = z;
    dcoef[(long long)bh * T_SEQ + s] = 0.25f * dsum;
}

// ---------------------------------------------------------------------------
// Per-tile max K row norm (over 96 used dims): Ktm[bh][tile].
// Main 64 dims summed exactly from stored bf16; ext cos/sin bounded by 4.1.
// grid (NTILE, 16), block 256: 4 threads/row.
// ---------------------------------------------------------------------------
__global__ __launch_bounds__(256)
void knorm_kernel(const u16t* __restrict__ Kbf, float* __restrict__ knorm)
{
    __shared__ float wmax[4];
    int tile = blockIdx.x, bh = blockIdx.y, tid = threadIdx.x;
    int row = tid >> 2, part = tid & 3;
    const u16t* rp = Kbf + ((long long)bh * T_SEQ + tile * 64 + row) * DP + part * 16;
    float ss = 0.f;
#pragma unroll
    for (int i = 0; i < 2; ++i) {
        s16x8 v = *(const s16x8*)(rp + i * 8);
#pragma unroll
        for (int e = 0; e < 8; ++e) { float f = bf2f((u16t)v[e]); ss += f * f; }
    }
    ss += __shfl_xor(ss, 1, 64);
    ss += __shfl_xor(ss, 2, 64);
    float nrm = sqrtf(ss + 4.1f);
#pragma unroll
    for (int off = 4; off < 64; off <<= 1) nrm = fmaxf(nrm, __shfl_xor(nrm, off, 64));
    if ((tid & 63) == 0) wmax[tid >> 6] = nrm;
    __syncthreads();
    if (tid == 0)
        knorm[bh * NTILE + tile] =
            fmaxf(fmaxf(wmax[0], wmax[1]), fmaxf(wmax[2], wmax[3]));
}

// ---------------------------------------------------------------------------
// MFMA flash attention with rigorous tile skipping.
// Band tiles (d<=1) always computed; others only if Cauchy-Schwarz bound
// qn*Ktm - dc*minDelta > mrun - 15 for any lane (else contribution < e^-15).
// ---------------------------------------------------------------------------
__global__ __launch_bounds__(256)
void attn_kernel(const u16t* __restrict__ Qbf, const u16t* __restrict__ Kbf,
                 const u16t* __restrict__ Vbf, const float* __restrict__ dcoef,
                 const float* __restrict__ knorm, u16t* __restrict__ Rt)
{
    __shared__ u16t Kt[2][64 * DP];       // 32KB
    __shared__ u16t Vt[2][64 * 64];       // 16KB
    __shared__ u16t Pl[4][16 * 64];       // 8KB
    __shared__ u32t voteLds[4];

    int bh = blockIdx.y, b = bh >> 3, h = bh & 7;
    int j0 = blockIdx.x;
    int s0 = j0 * 64;
    int tid = threadIdx.x, w = tid >> 6, lane = tid & 63;
    int l16 = lane & 15, l4 = lane >> 4;
    const u16t* Qg = Qbf + (long long)bh * T_SEQ * DP;
    const u16t* Kg = Kbf + (long long)bh * T_SEQ * DP;
    const u16t* Vg = Vbf + ((long long)b * C_DIM + h * HD) * T_SEQ;
    int sl = w * 16 + l16;
    int sg = s0 + sl;

    // Q B-fragments direct from global (contiguous 16B per lane)
    s16x8 qf[3];
#pragma unroll
    for (int kb = 0; kb < 3; ++kb)
        qf[kb] = *(const s16x8*)(Qg + (long long)sg * DP + kb * 32 + l4 * 8);
    // ||q|| over 96 dims (24 per lane, reduce across l4 groups)
    float qn2 = 0.f;
#pragma unroll
    for (int kb = 0; kb < 3; ++kb)
#pragma unroll
        for (int e = 0; e < 8; ++e) { float f = bf2f((u16t)qf[kb][e]); qn2 += f * f; }
    qn2 += __shfl_xor(qn2, 16, 64);
    qn2 += __shfl_xor(qn2, 32, 64);
    float qn = sqrtf(qn2);
    float dc = dcoef[(long long)bh * T_SEQ + sg];
    float mrun = -1e30f, lrun = 0.f;
    f32x4 O4[4] = {};

    auto stageKV = [&](int tt0, int bufi) {
#pragma unroll
        for (int i = 0; i < 4; ++i) {
            int rb = w * 16 + i * 4;
            int row = rb + (lane >> 4);
            int c = (lane & 15) ^ (row & 7);
            GLD16(Kg + (long long)(tt0 + row) * DP + c * 8, &Kt[bufi][rb * DP]);
        }
#pragma unroll
        for (int i = 0; i < 2; ++i) {
            int cb = w * 16 + i * 8;
            int cc = cb + (lane >> 3);
            int tc = (lane & 7) ^ (cc & 7);
            GLD16(Vg + (long long)cc * T_SEQ + tt0 + tc * 8, &Vt[bufi][cb * 64]);
        }
    };

    auto compute_tile = [&](int tj, int bufi, bool diag) {
        const u16t* Kb = Kt[bufi];
        const u16t* Vb = Vt[bufi];
        int t0 = tj * 64;
        f32x4 sacc[4] = {};
#pragma unroll
        for (int kb = 0; kb < 3; ++kb)
#pragma unroll
            for (int rt = 0; rt < 4; ++rt) {
                s16x8 af = *(const s16x8*)(&Kb[(rt * 16 + l16) * DP + (((kb * 4 + l4) ^ (l16 & 7)) * 8)]);
                sacc[rt] = __builtin_amdgcn_mfma_f32_16x16x32_bf16(af, qf[kb], sacc[rt], 0, 0, 0);
            }
        float cm = mrun;
        float pv[4][4];
#pragma unroll
        for (int rt = 0; rt < 4; ++rt) {
            int tb = t0 + rt * 16 + l4 * 4;
#pragma unroll
            for (int j = 0; j < 4; ++j) {
                int t = tb + j;
                float v = sacc[rt][j] - fabsf((float)(t - sg)) * dc;
                if (diag && t == sg) v = -100.f;
                pv[rt][j] = v;
                cm = fmaxf(cm, v);
            }
        }
        cm = fmaxf(cm, __shfl_xor(cm, 16, 64));
        cm = fmaxf(cm, __shfl_xor(cm, 32, 64));
        if (__any(cm > mrun)) {
            float scale = __expf(mrun - cm);
            mrun = cm;
            lrun *= scale;
#pragma unroll
            for (int rt = 0; rt < 4; ++rt) O4[rt] *= scale;
        }
        float psum = 0.f;
#pragma unroll
        for (int rt = 0; rt < 4; ++rt)
#pragma unroll
            for (int j = 0; j < 4; ++j) {
                float p = __expf(pv[rt][j] - mrun);
                pv[rt][j] = p;
                psum += p;
            }
        psum += __shfl_xor(psum, 16, 64);
        psum += __shfl_xor(psum, 32, 64);
        lrun += psum;
        // pack P^T (bf16, swizzled) into wave-local strip
#pragma unroll
        for (int rt = 0; rt < 4; ++rt) {
            int tl = rt * 16 + l4 * 4;
            int cp = (tl >> 3) ^ (l16 & 7);
            *(uint2*)(&Pl[w][l16 * 64 + cp * 8 + (tl & 7)]) =
                make_uint2(pack2(pv[rt][0], pv[rt][1]), pack2(pv[rt][2], pv[rt][3]));
        }
#pragma unroll
        for (int kb = 0; kb < 2; ++kb) {
            s16x8 pf = *(const s16x8*)(&Pl[w][l16 * 64 + (((kb * 4 + l4) ^ (l16 & 7)) * 8)]);
#pragma unroll
            for (int rt = 0; rt < 4; ++rt) {
                s16x8 vf = *(const s16x8*)(&Vb[(rt * 16 + l16) * 64 + (((kb * 4 + l4) ^ (l16 & 7)) * 8)]);
                O4[rt] = __builtin_amdgcn_mfma_f32_16x16x32_bf16(vf, pf, O4[rt], 0, 0, 0);
            }
        }
    };

    // ---- phase 1: diagonal band (establishes mrun) ----
    int seq[3]; int ns = 0;
    seq[ns++] = j0;
    if (j0 + 1 < NTILE) seq[ns++] = j0 + 1;
    if (j0 > 0) seq[ns++] = j0 - 1;
    stageKV(seq[0] * 64, 0);
    for (int i = 0; i < ns; ++i) {
        __syncthreads();
        if (i + 1 < ns) stageKV(seq[i + 1] * 64, (i + 1) & 1);
        compute_tile(seq[i], i & 1, seq[i] == j0);
    }

    // ---- phase 2: Cauchy-Schwarz bounds for remaining tiles ----
    u32t mask = 0;
    const float* knb = knorm + bh * NTILE;
    for (int j = 0; j < NTILE; ++j) {
        int d = j > j0 ? j - j0 : j0 - j;
        if (d <= 1) continue;
        float minD = (float)((d - 1) * 64 + 1);
        float bound = qn * knb[j] - dc * minD;
        if (__any(bound > mrun - 15.f)) mask |= 1u << j;
    }
    voteLds[w] = mask;
    __syncthreads();
    mask = voteLds[0] | voteLds[1] | voteLds[2] | voteLds[3];

    // ---- phase 3: compute surviving far tiles ----
    int parity = ns & 1;
    u32t rem = mask;
    if (rem) {
        int j = (int)__builtin_ctz(rem);
        stageKV(j * 64, parity);
        while (true) {
            rem &= rem - 1;
            __syncthreads();
            int nj = rem ? (int)__builtin_ctz(rem) : -1;
            if (nj >= 0) stageKV(nj * 64, parity ^ 1);
            compute_tile(j, parity, false);
            if (nj < 0) break;
            parity ^= 1;
            j = nj;
        }
    }

    // ---- epilogue: O/l -> bf16, LDS transpose bounce, coalesced store ----
    __syncthreads();
    float inv = 1.f / lrun;
#pragma unroll
    for (int rt = 0; rt < 4; ++rt) {
        O4[rt] *= inv;
        int cb = rt * 16 + l4 * 4;
        int cp = (cb >> 3) ^ (sl & 7);
        *(uint2*)(&Kt[0][sl * 64 + cp * 8 + (cb & 7)]) =
            make_uint2(pack2(O4[rt][0], O4[rt][1]), pack2(O4[rt][2], O4[rt][3]));
    }
    __syncthreads();
    {
        int row = tid >> 2;
        int rsw = row & 7;
        u16t* dst = Rt + ((long long)b * T_SEQ + s0 + row) * C_DIM + h * HD;
#pragma unroll
        for (int i = 0; i < 2; ++i) {
            int cc = (tid & 3) + i * 4;
            uint4 v = *(const uint4*)(&Kt[0][row * 64 + ((cc ^ rsw) * 8)]);
            *(uint4*)(dst + cc * 8) = v;
        }
    }
}

// ---------------------------------------------------------------------------
extern "C" void kernel_launch(void* const* d_in, const int* in_sizes, int n_in,
                              void* d_out, int out_size, void* d_ws, size_t ws_size,
                              hipStream_t stream)
{
    const float* x   = (const float*)d_in[0];
    const float* Wq  = (const float*)d_in[1];
    const float* bq  = (const float*)d_in[2];
    const float* Wk  = (const float*)d_in[3];
    const float* bk  = (const float*)d_in[4];
    const float* Wc  = (const float*)d_in[5];
    const float* bc  = (const float*)d_in[6];
    const float* Wqf = (const float*)d_in[7];
    const float* bqf = (const float*)d_in[8];
    const float* Wqd = (const float*)d_in[9];
    const float* bqd = (const float*)d_in[10];
    const float* Wp  = (const float*)d_in[11];
    const float* bp  = (const float*)d_in[12];
    float* out = (float*)d_out;

    char* p = (char*)d_ws;
    u16t* Wcat = (u16t*)p;    p += (long long)MTOT * C_DIM * 2;
    u16t* Wpbf = (u16t*)p;    p += (long long)C_DIM * C_DIM * 2;
    float* biascat = (float*)p; p += MTOT * 4;
    u16t* xT = (u16t*)p;      p += (long long)B_SZ * T_SEQ * C_DIM * 2;
    u16t* Qbf = (u16t*)p;     p += (long long)16 * T_SEQ * DP * 2;
    u16t* Kbf = (u16t*)p;     p += (long long)16 * T_SEQ * DP * 2;
    u16t* Vbf = (u16t*)p;     p += (long long)B_SZ * C_DIM * T_SEQ * 2;
    float* fqd = (float*)p;   p += (long long)B_SZ * 64 * T_SEQ * 4;
    float* dcoef = (float*)p; p += (long long)16 * T_SEQ * 4;
    float* knorm = (float*)p; p += (long long)16 * NTILE * 4;
    u16t* Rt = (u16t*)p;      p += (long long)B_SZ * T_SEQ * C_DIM * 2;

    dim3 blk(256);
    hipLaunchKernelGGL(wconv_kernel, dim3(MTOT + 512 + 1), blk, 0, stream,
                       Wq, Wk, Wc, Wqf, Wqd, Wp, bq, bk, bc, bqf, bqd,
                       Wcat, Wpbf, biascat);
    hipLaunchKernelGGL(xt_kernel, dim3(T_SEQ / 64, C_DIM / 64, B_SZ), blk, 0, stream,
                       x, xT);
    hipLaunchKernelGGL(gemm_kernel, dim3(T_SEQ / 64, MTOT / 64, B_SZ), blk, 0, stream,
                       Wcat, xT, biascat, nullptr, Qbf, Kbf, Vbf, fqd, nullptr, 0);
    hipLaunchKernelGGL(kext_kernel, dim3(T_SEQ / 256, 16), blk, 0, stream, Kbf);
    hipLaunchKernelGGL(coef_kernel, dim3(T_SEQ / 256, 16), blk, 0, stream,
                       fqd, Qbf, dcoef);
    hipLaunchKernelGGL(knorm_kernel, dim3(NTILE, 16), blk, 0, stream, Kbf, knorm);
    hipLaunchKernelGGL(attn_kernel, dim3(T_SEQ / 64, 16), blk, 0, stream,
                       Qbf, Kbf, Vbf, dcoef, knorm, Rt);
    hipLaunchKernelGGL(gemm_kernel, dim3(T_SEQ / 64, C_DIM / 64, B_SZ), blk, 0, stream,
                       Wpbf, Rt, bp, (const float*)x, nullptr, nullptr, nullptr, nullptr,
                       out, 1);
}